// Round 1
// baseline (20.768 us; speedup 1.0000x reference)
//
#include <hip/hip_runtime.h>
#include <math.h>

// Problem constants (from reference)
constexpr int B       = 256;
constexpr int C       = 8;
constexpr int LEN_TS  = 4096;
constexpr int K       = 128;
constexpr int DIM     = 3;
constexpr int START   = 0;          // max(0, 1000-1024)
constexpr int END     = 2152;       // min(4096, 1128+1024)
constexpr int PIS_LEN = END - START;        // 2152
constexpr int OUTW    = PIS_LEN - K + 1;    // 2025
constexpr float INV_NORM      = 0.1f;       // 1/NORM
constexpr float ALPHA         = -10.0f;
constexpr float BNORM         = 100.0f;
constexpr float MAX_CI        = 3.0f;
constexpr float MAX_NORM_DIST = 1e-5f;

constexpr int TPB    = 512;
constexpr int NWAVES = TPB / 64;

__global__ __launch_bounds__(TPB)
void pis_dist_block_kernel(const float* __restrict__ x,
                           const float* __restrict__ shapelet,
                           float* __restrict__ out) {
    __shared__ float s_pis[PIS_LEN];
    __shared__ float s_sh[K];
    __shared__ float s_red[2][NWAVES];

    const int b   = blockIdx.x;
    const int tid = threadIdx.x;

    // ---- stage pis (channel DIM slice) into LDS, float4 coalesced ----
    const float* xrow = x + ((size_t)b * C + DIM) * LEN_TS + START;  // 16B-aligned
    const float4* xr4 = reinterpret_cast<const float4*>(xrow);
    for (int i = tid; i < PIS_LEN / 4; i += TPB) {
        float4 v = xr4[i];
        s_pis[4 * i + 0] = v.x;
        s_pis[4 * i + 1] = v.y;
        s_pis[4 * i + 2] = v.z;
        s_pis[4 * i + 3] = v.w;
    }
    if (tid < K) s_sh[tid] = shapelet[tid];
    __syncthreads();

    // ---- ci_sh (redundant per-thread, pure LDS broadcast reads) ----
    float ci_sh = 0.0f;
    #pragma unroll 8
    for (int i = 0; i < K - 1; ++i) {
        float d = s_sh[i + 1] - s_sh[i];
        ci_sh += d * d;
    }
    ci_sh += INV_NORM;

    // ---- windows ----
    float wd_sum = 0.0f;
    float w_sum  = 0.0f;
    for (int o = tid; o < OUTW; o += TPB) {
        float prev  = s_pis[o];
        float df0   = prev - s_sh[0];
        float sumsq = df0 * df0;
        float sumd2 = 0.0f;
        #pragma unroll 8
        for (int k = 1; k < K; ++k) {
            float p  = s_pis[o + k];
            float df = p - s_sh[k];
            sumsq    = fmaf(df, df, sumsq);
            float dd = p - prev;
            sumd2    = fmaf(dd, dd, sumd2);
            prev     = p;
        }
        float ci_pis  = sumd2 + INV_NORM;
        float mx      = fmaxf(ci_pis, ci_sh);
        float mn      = fminf(ci_pis, ci_sh);
        float ci_dist = fminf(mx / mn, MAX_CI);
        float dist    = sumsq * ci_dist * (1.0f / (float)K);
        float d       = dist * (1.0f / BNORM);
        float w       = __expf(ALPHA * d);
        wd_sum += w * d;
        w_sum  += w;
    }

    // ---- reduce across 64-lane waves, then across waves ----
    #pragma unroll
    for (int off = 32; off > 0; off >>= 1) {
        wd_sum += __shfl_down(wd_sum, off);
        w_sum  += __shfl_down(w_sum, off);
    }
    const int lane = tid & 63;
    const int wv   = tid >> 6;
    if (lane == 0) {
        s_red[0][wv] = wd_sum;
        s_red[1][wv] = w_sum;
    }
    __syncthreads();
    if (tid == 0) {
        float wd = 0.0f, w = 0.0f;
        #pragma unroll
        for (int i = 0; i < NWAVES; ++i) {
            wd += s_red[0][i];
            w  += s_red[1][i];
        }
        float softmin = wd / w * BNORM;
        out[b] = 1.0f - softmin / MAX_NORM_DIST;
    }
}

extern "C" void kernel_launch(void* const* d_in, const int* in_sizes, int n_in,
                              void* d_out, int out_size, void* d_ws, size_t ws_size,
                              hipStream_t stream) {
    const float* x        = (const float*)d_in[0];
    const float* shapelet = (const float*)d_in[1];
    float* out            = (float*)d_out;
    pis_dist_block_kernel<<<B, TPB, 0, stream>>>(x, shapelet, out);
}